// Round 11
// baseline (307.541 us; speedup 1.0000x reference)
//
#include <hip/hip_runtime.h>
#include <hip/hip_bf16.h>

typedef unsigned short u16;
typedef _Float16 f16x8 __attribute__((ext_vector_type(8)));
typedef unsigned short u16x8 __attribute__((ext_vector_type(8)));
typedef float f32x4 __attribute__((ext_vector_type(4)));

#define SQHF 0.70710678118654752440f

__device__ __forceinline__ u16 f2h(float f) {
  const _Float16 h = (_Float16)f;  // RNE
  return __builtin_bit_cast(u16, h);
}

template <int N>
__device__ __forceinline__ void vmwait() {
  asm volatile("s_waitcnt vmcnt(%0)" ::"i"(N) : "memory");
}

// async global->LDS, 16B per lane; LDS dest is wave-uniform base + lane*16
__device__ __forceinline__ void gload_lds16(const void* g, void* l) {
  __builtin_amdgcn_global_load_lds(
      (const __attribute__((address_space(1))) unsigned int*)g,
      (__attribute__((address_space(3))) unsigned int*)l, 16, 0, 0);
}

__device__ __forceinline__ float block_sum(float v) {
#pragma unroll
  for (int o = 32; o; o >>= 1) v += __shfl_xor(v, o);
  __shared__ float red[4];
  if ((threadIdx.x & 63) == 0) red[threadIdx.x >> 6] = v;
  __syncthreads();
  return red[0] + red[1] + red[2] + red[3];
}

// weight-norm of in_v rows (dim E over C), store TRANSPOSED f16 Wt[c][e]
__global__ void wnorm_t_kernel(const float* __restrict__ v, const float* __restrict__ g,
                               u16* __restrict__ wtf) {
  const int e = blockIdx.x;
  const float* vr = v + (long)e * 1024;
  float ss = 0.f;
  for (int c = threadIdx.x; c < 1024; c += 256) { float t = vr[c]; ss += t * t; }
  const float tot = block_sum(ss);
  const float scl = g[e] / sqrtf(tot);
  for (int c = threadIdx.x; c < 1024; c += 256) wtf[(long)c * 1024 + e] = f2h(vr[c] * scl);
}

// weight-norm of out_v rows (dim C over E), natural layout f16 (A for Zo GEMM)
__global__ void wnorm_kernel(const float* __restrict__ v, const float* __restrict__ g,
                             u16* __restrict__ w) {
  const int c = blockIdx.x;
  const float* vr = v + (long)c * 1024;
  float ss = 0.f;
  for (int e = threadIdx.x; e < 1024; e += 256) { float t = vr[e]; ss += t * t; }
  const float tot = block_sum(ss);
  const float scl = g[c] / sqrtf(tot);
  for (int e = threadIdx.x; e < 1024; e += 256) w[(long)c * 1024 + e] = f2h(vr[e] * scl);
}

// conv_feats [B,1024,196] -> y_t f16 into concat cols 1024..2047 (rows v>=196 zero)
// + rc[b][v] += sum_{e in chunk} in_b[e]*y[b,e,v] via f32 atomics (rc pre-zeroed).
__global__ void prep_y_kernel(const float* __restrict__ conv, const float* __restrict__ in_b,
                              u16* __restrict__ concat, float* __restrict__ rc) {
  const int b = blockIdx.x >> 4;
  const int e0 = (blockIdx.x & 15) << 6;
  __shared__ float tile[64 * 224];
  const float* cb = conv + ((long)b * 1024 + e0) * 196;
  for (int idx = threadIdx.x; idx < 64 * 224; idx += 256) {
    const int rr = idx / 224, vv = idx - rr * 224;
    tile[idx] = (vv < 196) ? cb[(long)rr * 196 + vv] : 0.f;
  }
  __syncthreads();
  for (int idx = threadIdx.x; idx < 256 * 64; idx += 256) {
    const int vr = idx >> 6, c = idx & 63;
    const float val = (vr < 224) ? tile[c * 224 + vr] : 0.f;
    concat[((long)b * 256 + vr) * 2048 + 1024 + e0 + c] = f2h(val);
  }
  const int v = threadIdx.x;
  if (v < 196) {
    float s = 0.f;
#pragma unroll 8
    for (int rr = 0; rr < 64; ++rr) s += in_b[e0 + rr] * tile[rr * 224 + v];
    atomicAdd(&rc[b * 256 + v], s);
  }
}

// scores = s0+s1 (K-split halves) +rc, *sqrt(1/2) -> attn f32 [M][196] + attn f16 [M][256]
__global__ void softmax_kernel(const float* __restrict__ s0b, const float* __restrict__ s1b,
                               const float* __restrict__ rc,
                               float* __restrict__ attn, u16* __restrict__ attn_f) {
  const long row = (long)blockIdx.x * 4 + (threadIdx.x >> 6);
  const int lane = threadIdx.x & 63;
  const int b = (int)(row >> 10);
  const float* s0 = s0b + row * 256;
  const float* s1 = s1b + row * 256;
  const float* rcb = rc + b * 256;
  float v0 = (s0[lane] + s1[lane] + rcb[lane]) * SQHF;
  float v1 = (s0[64 + lane] + s1[64 + lane] + rcb[64 + lane]) * SQHF;
  float v2 = (s0[128 + lane] + s1[128 + lane] + rcb[128 + lane]) * SQHF;
  float v3 = (lane < 4) ? (s0[192 + lane] + s1[192 + lane] + rcb[192 + lane]) * SQHF : -1e30f;
  float mx = fmaxf(fmaxf(v0, v1), fmaxf(v2, v3));
#pragma unroll
  for (int o = 32; o; o >>= 1) mx = fmaxf(mx, __shfl_xor(mx, o));
  const float e0 = __expf(v0 - mx), e1 = __expf(v1 - mx), e2 = __expf(v2 - mx);
  const float e3 = (lane < 4) ? __expf(v3 - mx) : 0.f;
  float sm = e0 + e1 + e2 + e3;
#pragma unroll
  for (int o = 32; o; o >>= 1) sm += __shfl_xor(sm, o);
  const float inv = 1.f / sm;
  float* arow = attn + row * 196;
  arow[lane] = e0 * inv;
  arow[64 + lane] = e1 * inv;
  arow[128 + lane] = e2 * inv;
  if (lane < 4) arow[192 + lane] = e3 * inv;
  u16* brow = attn_f + row * 256;
  brow[lane] = f2h(e0 * inv);
  brow[64 + lane] = f2h(e1 * inv);
  brow[128 + lane] = f2h(e2 * inv);
  brow[192 + lane] = (lane < 4) ? f2h(e3 * inv) : (u16)0;
}

// 128x128-tile fp16 MFMA GEMM, B^T-layout operands, T4 counted-vmcnt pipeline
// (2 buffers, 2 raw barriers/iter, no vmcnt(0) in steady state).
// MODE 3: A,B both f16 from global via global_load_lds. 4 loads/stage.
// MODE 2: A from f32 global via T14 REG-STAGING (4x global_load_dwordx4 ->
//   16x cvt f16 -> 2x ds_write_b128 into the same swizzled layout), B via
//   global_load_lds. 6 vm-ops/stage. R10 post-mortem: staging A as f32 in LDS
//   (24KB/buf, 48KB total) capped residency at 3 blocks/CU -> latency-bound at
//   27% occupancy. f16 A-tile halves LDS to 16KB/buf = 32KB -> grid's 4
//   blocks/CU all resident. Steady-state counts (A issued before B):
//   vmcnt(6) before barrier-1 retires B(t); vmcnt(2) after barrier-2 retires
//   A(t+1) regs for ds_write; then issue A(t+2)+B(t+2) (8 outstanding max).
// Both f16 LDS tiles use chunk-XOR swizzle (row>>1)&3 on write/src AND read.
// kSplit2: grid doubled; half=bid&1 selects K-half (kOff=half*1024), EPI3 target.
// EPI: 1=(acc+bias[col]+extra[row*ldOut+col])*scale -> f32
//      3=acc -> f32 (out1/out2 by half);  6=(_Float16)(acc*scale) -> f16
// NOTE: NO min-waves clause (R3: (256,4)->spills; R4: (256,2)->lost ILP).
template <int EPI, int MODE>
__global__ __launch_bounds__(256) void gemm128(
    const u16* __restrict__ Ah,
    const float* __restrict__ Af0, const float* __restrict__ Af1, int kSw,
    const u16* __restrict__ Bh,
    int N, int K, int ldA, int ldB, int ldOut,
    int mTilesPerBatch, long bStride, int aTilesMod, int kSplit2,
    const float* __restrict__ bias, const float* __restrict__ extra,
    float scale, void* __restrict__ out1, void* __restrict__ out2) {
  constexpr int AREG = (MODE == 2);
  constexpr int TBH = 4096;   // B tile base (u16 slots)
  constexpr int HSM = 8192;   // per-buffer u16 slots (16KB)
  __shared__ __align__(16) u16 smem[HSM * 2];

  int bid = blockIdx.x, nwg = gridDim.x, half = 0;
  if (kSplit2) { half = bid & 1; bid >>= 1; nwg >>= 1; }
  const int kOff = half << 10;

  const int numN = N >> 7;
  const int q = nwg >> 3, r = nwg & 7, xcd = bid & 7, l8 = bid >> 3;
  const int wg = (xcd < r ? xcd * (q + 1) : r * (q + 1) + (xcd - r) * q) + l8;
  const int mTile = wg / numN, nTile = wg - mTile * numN;
  const long rowBase = (long)mTile << 7;
  const int colBase = nTile << 7;
  const int aTile = aTilesMod ? (mTile % aTilesMod) : mTile;
  const long aRowBase = (long)aTile << 7;
  const long bOff = mTilesPerBatch ? (long)(mTile / mTilesPerBatch) * bStride : 0;

  const u16* Agh = AREG ? nullptr : (Ah + aRowBase * ldA);
  const u16* Bgh = Bh + bOff + (long)colBase * ldB;

  const int tid = threadIdx.x;
  const int wave = tid >> 6, lane = tid & 63;
  const int wr = wave >> 1, wc = wave & 1;
  const int sr = wave * 16 + (lane >> 2);      // staged LDS row (within 64-row half)
  const int scS = (((lane & 3) ^ ((sr >> 1) & 3)) << 3);  // swizzled global u16 col
  const int lr = lane & 15;

  f32x4 acc[4][4];
#pragma unroll
  for (int m = 0; m < 4; ++m)
#pragma unroll
    for (int n = 0; n < 4; ++n) acc[m][n] = f32x4{0.f, 0.f, 0.f, 0.f};

  auto stageB = [&](int buf, int k0) {
    u16* sb = smem + buf * HSM;
#pragma unroll
    for (int i = 0; i < 2; ++i) {
      const long ro = (long)(i * 64 + sr) * ldB + k0 + kOff + scS;
      gload_lds16(Bgh + ro, &sb[TBH + i * 2048 + wave * 512]);
    }
  };
  auto stageA_lds = [&](int buf, int k0) {
    u16* sb = smem + buf * HSM;
#pragma unroll
    for (int i = 0; i < 2; ++i) {
      const long ro = (long)(i * 64 + sr) * ldA + k0 + kOff + scS;
      gload_lds16(Agh + ro, &sb[i * 2048 + wave * 512]);
    }
  };

  auto compute = [&](int buf) {
    const u16* sb = smem + buf * HSM;
    f16x8 fa[4], fb[4];
#pragma unroll
    for (int m = 0; m < 4; ++m) {
      const int row = wr * 64 + m * 16 + lr;
      const int off = row * 32 + (((lane >> 4) ^ ((row >> 1) & 3)) << 3);
      fa[m] = __builtin_bit_cast(f16x8, *(const u16x8*)&sb[off]);
    }
#pragma unroll
    for (int n = 0; n < 4; ++n) {
      const int row = wc * 64 + n * 16 + lr;
      const int off = row * 32 + (((lane >> 4) ^ ((row >> 1) & 3)) << 3);
      fb[n] = __builtin_bit_cast(f16x8, *(const u16x8*)&sb[TBH + off]);
    }
    __builtin_amdgcn_s_setprio(1);
#pragma unroll
    for (int m = 0; m < 4; ++m)
#pragma unroll
      for (int n = 0; n < 4; ++n)
        acc[m][n] = __builtin_amdgcn_mfma_f32_16x16x32_f16(fa[m], fb[n], acc[m][n], 0, 0, 0);
    __builtin_amdgcn_s_setprio(0);
  };

  const int nSteps = K >> 5;

  if constexpr (AREG) {
    // A reg-staging geometry: thread handles chunks (arow,akch) and (arow+64,akch);
    // each chunk = 8 consecutive f32 -> one 8xf16 ds_write_b128.
    const int arow = tid >> 2, akch = tid & 3;
    const int r1 = arow + 64;
    const int aoff0 = arow * 32 + ((akch ^ ((arow >> 1) & 3)) << 3);
    const int aoff1 = r1 * 32 + ((akch ^ ((r1 >> 1) & 3)) << 3);
    f32x4 ra0, ra1, rb0, rb1;  // single named set, lifetime ~1 iteration (rule #20)
    auto issueA = [&](int k0) {
      const int gk = k0 + kOff;
      const float* As = (gk < kSw) ? (Af0 + aRowBase * (long)ldA + gk)
                                   : (Af1 + aRowBase * (long)ldA + (gk - kSw));
      const float* p0 = As + (long)arow * ldA + akch * 8;
      const float* p1 = As + (long)r1 * ldA + akch * 8;
      ra0 = *(const f32x4*)p0; ra1 = *(const f32x4*)(p0 + 4);
      rb0 = *(const f32x4*)p1; rb1 = *(const f32x4*)(p1 + 4);
    };
    auto writeA = [&](int buf) {
      u16* sb = smem + buf * HSM;
      u16x8 w0, w1;
      w0[0] = f2h(ra0[0]); w0[1] = f2h(ra0[1]); w0[2] = f2h(ra0[2]); w0[3] = f2h(ra0[3]);
      w0[4] = f2h(ra1[0]); w0[5] = f2h(ra1[1]); w0[6] = f2h(ra1[2]); w0[7] = f2h(ra1[3]);
      w1[0] = f2h(rb0[0]); w1[1] = f2h(rb0[1]); w1[2] = f2h(rb0[2]); w1[3] = f2h(rb0[3]);
      w1[4] = f2h(rb1[0]); w1[5] = f2h(rb1[1]); w1[6] = f2h(rb1[2]); w1[7] = f2h(rb1[3]);
      *(u16x8*)&sb[aoff0] = w0;
      *(u16x8*)&sb[aoff1] = w1;
    };
    issueA(0); stageB(0, 0);                  // 6 outstanding
    vmwait<2>();                              // A(0) regs landed (B(0) may fly)
    writeA(0);
    if (nSteps > 1) { issueA(32); stageB(1, 32); }  // 8 outstanding
    for (int t = 0; t < nSteps; ++t) {
      if (t + 1 < nSteps) {
        asm volatile("s_waitcnt vmcnt(6) lgkmcnt(0)" ::: "memory");  // B(t)+A-writes done
      } else {
        asm volatile("s_waitcnt vmcnt(0) lgkmcnt(0)" ::: "memory");
      }
      __builtin_amdgcn_s_barrier();
      __builtin_amdgcn_sched_barrier(0);      // rule #18 fence
      compute(t & 1);
      __builtin_amdgcn_sched_barrier(0);
      __builtin_amdgcn_s_barrier();
      if (t + 1 < nSteps) {
        vmwait<2>();                          // A(t+1) regs landed
        writeA((t + 1) & 1);
        if (t + 2 < nSteps) { issueA((t + 2) << 5); stageB(t & 1, (t + 2) << 5); }
      }
    }
  } else {
    stageA_lds(0, 0); stageB(0, 0);
    for (int t = 0; t < nSteps; ++t) {
      const int cur = t & 1;
      if (t + 1 < nSteps) {
        stageA_lds(cur ^ 1, (t + 1) << 5);
        stageB(cur ^ 1, (t + 1) << 5);
        vmwait<4>();                          // batch t landed
      } else {
        vmwait<0>();
      }
      __builtin_amdgcn_s_barrier();
      __builtin_amdgcn_sched_barrier(0);
      compute(cur);
      __builtin_amdgcn_sched_barrier(0);
      __builtin_amdgcn_s_barrier();
    }
  }

  const int rloc = (lane >> 4) << 2;
  float* o3 = (float*)(half ? out2 : out1);
#pragma unroll
  for (int m = 0; m < 4; ++m) {
#pragma unroll
    for (int n = 0; n < 4; ++n) {
      const int col = colBase + wc * 64 + n * 16 + lr;
#pragma unroll
      for (int j = 0; j < 4; ++j) {
        const long row = rowBase + wr * 64 + m * 16 + rloc + j;
        const float v = acc[m][n][j];
        if (EPI == 1) {
          ((float*)out1)[row * (long)ldOut + col] =
              (v + bias[col] + extra[row * (long)ldOut + col]) * scale;
        } else if (EPI == 3) {
          o3[row * (long)ldOut + col] = v;
        } else if (EPI == 6) {
          ((u16*)out1)[row * (long)ldOut + col] = f2h(v * scale);
        }
      }
    }
  }
}

extern "C" void kernel_launch(void* const* d_in, const int* in_sizes, int n_in,
                              void* d_out, int out_size, void* d_ws, size_t ws_size,
                              hipStream_t stream) {
  (void)in_sizes; (void)n_in; (void)out_size; (void)ws_size;
  const float* x     = (const float*)d_in[0];
  const float* we    = (const float*)d_in[1];
  const float* conv  = (const float*)d_in[2];
  const float* in_v  = (const float*)d_in[3];
  const float* in_g  = (const float*)d_in[4];
  const float* in_b  = (const float*)d_in[5];
  const float* out_v = (const float*)d_in[6];
  const float* out_g = (const float*)d_in[7];
  const float* out_b = (const float*)d_in[8];
  float* out  = (float*)d_out;
  float* attn = out + 33554432l;  // B*L*C floats, then B*L*196

  char* ws = (char*)d_ws;
  u16* concat = (u16*)(ws);                  // f16 [32][256][2048]: cols 0..1023 Zi | 1024.. y
  u16* wtf    = (u16*)(ws + 33554432l);      // Wt f16 [1024][1024] (transposed Wi)
  u16* wo     = (u16*)(ws + 35651584l);      // Wo f16 [1024][1024]
  u16* zo     = (u16*)(ws + 37748736l);      // Zo f16 [32][1024][256] (x14 folded)
  u16* attf   = (u16*)(ws + 54525952l);      // attn f16 [32768][256]
  float* rc   = (float*)(ws + 71303168l);    // [32][256]
  float* s1   = (float*)(ws + 71368704l);    // K-split half-1 scores [32768][256]
  float* s0   = out;                         // K-split half-0 scores in out region

  hipMemsetAsync(rc, 0, 32 * 256 * sizeof(float), stream);
  wnorm_t_kernel<<<1024, 256, 0, stream>>>(in_v, in_g, wtf);
  wnorm_kernel<<<1024, 256, 0, stream>>>(out_v, out_g, wo);
  prep_y_kernel<<<512, 256, 0, stream>>>(conv, in_b, concat, rc);
  // Zi^T[b*256+v][c] = sum_e y[b][v][e] * Wt[c][e], single-f16 MFMA,
  // A = y half of concat, out f16 into concat cols 0..1023 (M=8192,N=1024,K=1024)
  gemm128<6, 3><<<512, 256, 0, stream>>>(
      concat + 1024, nullptr, nullptr, 0, wtf,
      1024, 1024, 2048, 1024, 2048, 0, 0, 0, 0, nullptr, nullptr, 1.f, concat, nullptr);
  // scores = [x|we] @ [Zi;y], f16 MFMA, K-split halves (grid 2x512):
  // half0: x@Zi -> s0 ; half1: we@y -> s1  (per-half K=1024; A f32->f16 reg-staged)
  gemm128<3, 2><<<1024, 256, 0, stream>>>(
      nullptr, x, we, 1024, concat,
      256, 1024, 1024, 2048, 256, 8, 524288l, 0, 1, nullptr, nullptr, 1.f, s0, s1);
  softmax_kernel<<<8192, 256, 0, stream>>>(s0, s1, rc, attn, attf);
  // Zo[b*1024+c][v] = 14 * sum_e Wo[c][e] * y[b][v][e] -> f16
  // (M=32768,N=256,K=1024; A=Wo replicated per batch, B=y half of concat batched)
  gemm128<6, 3><<<512, 256, 0, stream>>>(
      wo, nullptr, nullptr, 0, concat + 1024,
      256, 1024, 1024, 2048, 256, 8, 524288l, 8, 0, nullptr, nullptr, 14.f, zo, nullptr);
  // out = (attf @ Zo^T + out_b + x) * sqrt(0.5)  (M=32768, N=1024, K=256)
  gemm128<1, 3><<<2048, 256, 0, stream>>>(
      attf, nullptr, nullptr, 0, zo,
      1024, 256, 256, 256, 1024, 8, 262144l, 0, 0, out_b, x, SQHF, out, nullptr);
}

// Round 12
// 304.176 us; speedup vs baseline: 1.0111x; 1.0111x over previous
//
#include <hip/hip_runtime.h>
#include <hip/hip_bf16.h>

typedef unsigned short u16;
typedef _Float16 f16x8 __attribute__((ext_vector_type(8)));
typedef unsigned short u16x8 __attribute__((ext_vector_type(8)));
typedef float f32x4 __attribute__((ext_vector_type(4)));

#define SQHF 0.70710678118654752440f

__device__ __forceinline__ u16 f2h(float f) {
  const _Float16 h = (_Float16)f;  // RNE
  return __builtin_bit_cast(u16, h);
}

template <int N>
__device__ __forceinline__ void vmwait() {
  asm volatile("s_waitcnt vmcnt(%0)" ::"i"(N) : "memory");
}

// async global->LDS, 16B per lane; LDS dest is wave-uniform base + lane*16
__device__ __forceinline__ void gload_lds16(const void* g, void* l) {
  __builtin_amdgcn_global_load_lds(
      (const __attribute__((address_space(1))) unsigned int*)g,
      (__attribute__((address_space(3))) unsigned int*)l, 16, 0, 0);
}

__device__ __forceinline__ float block_sum(float v) {
#pragma unroll
  for (int o = 32; o; o >>= 1) v += __shfl_xor(v, o);
  __shared__ float red[4];
  if ((threadIdx.x & 63) == 0) red[threadIdx.x >> 6] = v;
  __syncthreads();
  return red[0] + red[1] + red[2] + red[3];
}

// weight-norm of in_v rows (dim E over C), store TRANSPOSED f16 Wt[c][e]
__global__ void wnorm_t_kernel(const float* __restrict__ v, const float* __restrict__ g,
                               u16* __restrict__ wtf) {
  const int e = blockIdx.x;
  const float* vr = v + (long)e * 1024;
  float ss = 0.f;
  for (int c = threadIdx.x; c < 1024; c += 256) { float t = vr[c]; ss += t * t; }
  const float tot = block_sum(ss);
  const float scl = g[e] / sqrtf(tot);
  for (int c = threadIdx.x; c < 1024; c += 256) wtf[(long)c * 1024 + e] = f2h(vr[c] * scl);
}

// weight-norm of out_v rows (dim C over E), natural layout f16 (A for Zo GEMM)
__global__ void wnorm_kernel(const float* __restrict__ v, const float* __restrict__ g,
                             u16* __restrict__ w) {
  const int c = blockIdx.x;
  const float* vr = v + (long)c * 1024;
  float ss = 0.f;
  for (int e = threadIdx.x; e < 1024; e += 256) { float t = vr[e]; ss += t * t; }
  const float tot = block_sum(ss);
  const float scl = g[c] / sqrtf(tot);
  for (int e = threadIdx.x; e < 1024; e += 256) w[(long)c * 1024 + e] = f2h(vr[e] * scl);
}

// conv_feats [B,1024,196] -> y_t f16 into concat cols 1024..2047 (rows v>=196 zero)
// + rc[b][v] += sum_{e in chunk} in_b[e]*y[b,e,v] via f32 atomics (rc pre-zeroed).
__global__ void prep_y_kernel(const float* __restrict__ conv, const float* __restrict__ in_b,
                              u16* __restrict__ concat, float* __restrict__ rc) {
  const int b = blockIdx.x >> 4;
  const int e0 = (blockIdx.x & 15) << 6;
  __shared__ float tile[64 * 224];
  const float* cb = conv + ((long)b * 1024 + e0) * 196;
  for (int idx = threadIdx.x; idx < 64 * 224; idx += 256) {
    const int rr = idx / 224, vv = idx - rr * 224;
    tile[idx] = (vv < 196) ? cb[(long)rr * 196 + vv] : 0.f;
  }
  __syncthreads();
  for (int idx = threadIdx.x; idx < 256 * 64; idx += 256) {
    const int vr = idx >> 6, c = idx & 63;
    const float val = (vr < 224) ? tile[c * 224 + vr] : 0.f;
    concat[((long)b * 256 + vr) * 2048 + 1024 + e0 + c] = f2h(val);
  }
  const int v = threadIdx.x;
  if (v < 196) {
    float s = 0.f;
#pragma unroll 8
    for (int rr = 0; rr < 64; ++rr) s += in_b[e0 + rr] * tile[rr * 224 + v];
    atomicAdd(&rc[b * 256 + v], s);
  }
}

// scores = s0+s1 (K-split halves) +rc, *sqrt(1/2) -> attn f32 [M][196] + attn f16 [M][256]
__global__ void softmax_kernel(const float* __restrict__ s0b, const float* __restrict__ s1b,
                               const float* __restrict__ rc,
                               float* __restrict__ attn, u16* __restrict__ attn_f) {
  const long row = (long)blockIdx.x * 4 + (threadIdx.x >> 6);
  const int lane = threadIdx.x & 63;
  const int b = (int)(row >> 10);
  const float* s0 = s0b + row * 256;
  const float* s1 = s1b + row * 256;
  const float* rcb = rc + b * 256;
  float v0 = (s0[lane] + s1[lane] + rcb[lane]) * SQHF;
  float v1 = (s0[64 + lane] + s1[64 + lane] + rcb[64 + lane]) * SQHF;
  float v2 = (s0[128 + lane] + s1[128 + lane] + rcb[128 + lane]) * SQHF;
  float v3 = (lane < 4) ? (s0[192 + lane] + s1[192 + lane] + rcb[192 + lane]) * SQHF : -1e30f;
  float mx = fmaxf(fmaxf(v0, v1), fmaxf(v2, v3));
#pragma unroll
  for (int o = 32; o; o >>= 1) mx = fmaxf(mx, __shfl_xor(mx, o));
  const float e0 = __expf(v0 - mx), e1 = __expf(v1 - mx), e2 = __expf(v2 - mx);
  const float e3 = (lane < 4) ? __expf(v3 - mx) : 0.f;
  float sm = e0 + e1 + e2 + e3;
#pragma unroll
  for (int o = 32; o; o >>= 1) sm += __shfl_xor(sm, o);
  const float inv = 1.f / sm;
  float* arow = attn + row * 196;
  arow[lane] = e0 * inv;
  arow[64 + lane] = e1 * inv;
  arow[128 + lane] = e2 * inv;
  if (lane < 4) arow[192 + lane] = e3 * inv;
  u16* brow = attn_f + row * 256;
  brow[lane] = f2h(e0 * inv);
  brow[64 + lane] = f2h(e1 * inv);
  brow[128 + lane] = f2h(e2 * inv);
  brow[192 + lane] = (lane < 4) ? f2h(e3 * inv) : (u16)0;
}

// fp16 MFMA GEMM, B^T-layout operands, T4 counted-vmcnt pipeline (R8-validated:
// per step {stage(next); vmcnt(LPS); s_barrier; compute; s_barrier}).
// MODE 3: 128x128 tile; A,B f16 via global_load_lds; 4 loads/stage; 32KB LDS.
// MODE 2: 256x128 tile (SCORES). R11 post-mortem: per-step wall cost is
//   schedule-invariant (111-145us across single-buf/dbuf/counted/depth3/
//   reg-staged) -> amortize it: M doubled per block, grid 512 = ALL blocks
//   resident at 2/CU (80KB LDS), FLOPs/step x2. A staged as f32 (XOR-swizzled,
//   8 gloads), cvt->f16 in-register at fragment load; B f16 (2 gloads);
//   LPS=10.
// f16 LDS tiles use chunk-XOR swizzle (row>>1)&3 on both stage-src and read.
// kSplit2: grid doubled; half=bid&1 selects K-half (kOff=half*1024), EPI3 target.
// EPI: 1=(acc+bias[col]+extra[row*ldOut+col])*scale -> f32
//      3=acc -> f32 (out1/out2 by half);  6=(_Float16)(acc*scale) -> f16
// NOTE: NO min-waves clause (R3: (256,4)->spills; R4: (256,2)->lost ILP).
template <int EPI, int MODE>
__global__ __launch_bounds__(256) void gemm128(
    const u16* __restrict__ Ah,
    const float* __restrict__ Af0, const float* __restrict__ Af1, int kSw,
    const u16* __restrict__ Bh,
    int N, int K, int ldA, int ldB, int ldOut,
    int mTilesPerBatch, long bStride, int aTilesMod, int kSplit2,
    const float* __restrict__ bias, const float* __restrict__ extra,
    float scale, void* __restrict__ out1, void* __restrict__ out2) {
  constexpr int AF32 = (MODE == 2);
  constexpr int MROWS = AF32 ? 256 : 128;     // block tile M
  constexpr int MFRAG = AF32 ? 8 : 4;         // m-fragments per wave
  constexpr int LPS = AF32 ? 10 : 4;          // vm-ops per wave per stage
  constexpr int TBH = AF32 ? 16384 : 4096;    // B tile base (u16 slots)
  constexpr int HSM = AF32 ? 20480 : 8192;    // per-buffer u16 slots
  __shared__ __align__(16) u16 smem[HSM * 2];

  int bid = blockIdx.x, nwg = gridDim.x, half = 0;
  if (kSplit2) { half = bid & 1; bid >>= 1; nwg >>= 1; }
  const int kOff = half << 10;

  const int numN = N >> 7;
  const int q = nwg >> 3, r = nwg & 7, xcd = bid & 7, l8 = bid >> 3;
  const int wg = (xcd < r ? xcd * (q + 1) : r * (q + 1) + (xcd - r) * q) + l8;
  const int mTile = wg / numN, nTile = wg - mTile * numN;
  const long rowBase = (long)mTile * MROWS;
  const int colBase = nTile << 7;
  const int aTile = aTilesMod ? (mTile % aTilesMod) : mTile;
  const long aRowBase = (long)aTile * MROWS;
  const long bOff = mTilesPerBatch ? (long)(mTile / mTilesPerBatch) * bStride : 0;

  const u16* Agh = AF32 ? nullptr : (Ah + aRowBase * ldA);
  const u16* Bgh = Bh + bOff + (long)colBase * ldB;

  const int tid = threadIdx.x;
  const int wave = tid >> 6, lane = tid & 63;
  const int wr = wave >> 1, wc = wave & 1;
  const int sr = wave * 16 + (lane >> 2);      // staged LDS row (within 64-row half)
  const int scS = (((lane & 3) ^ ((sr >> 1) & 3)) << 3);  // swizzled global u16 col
  const int lr = lane & 15;
  const int lk = (lane >> 4) << 3;

  f32x4 acc[MFRAG][4];
#pragma unroll
  for (int m = 0; m < MFRAG; ++m)
#pragma unroll
    for (int n = 0; n < 4; ++n) acc[m][n] = f32x4{0.f, 0.f, 0.f, 0.f};

  auto stage = [&](int buf, int k0) {
    u16* sb = smem + buf * HSM;
    if (AF32) {
      const int gk = k0 + kOff;
      const float* As = (gk < kSw) ? (Af0 + aRowBase * (long)ldA + gk)
                                   : (Af1 + aRowBase * (long)ldA + (gk - kSw));
      const int rr = tid >> 3;
#pragma unroll
      for (int i = 0; i < 8; ++i) {           // 256 rows x 32 f32
        const int row = i * 32 + rr;
        const int csw = (((tid & 7) ^ (row & 7)) << 2);  // XOR-swizzled f32 col
        gload_lds16(As + (long)row * ldA + csw, &sb[i * 2048 + wave * 512]);
      }
#pragma unroll
      for (int i = 0; i < 2; ++i) {           // 128 rows x 32 f16
        const long ro = (long)(i * 64 + sr) * ldB + k0 + kOff + scS;
        gload_lds16(Bgh + ro, &sb[TBH + i * 2048 + wave * 512]);
      }
    } else {
#pragma unroll
      for (int i = 0; i < 2; ++i) {
        const long roA = (long)(i * 64 + sr) * ldA + k0 + kOff + scS;
        const long roB = (long)(i * 64 + sr) * ldB + k0 + kOff + scS;
        const int lo_ = i * 2048 + wave * 512;
        gload_lds16(Agh + roA, &sb[lo_]);
        gload_lds16(Bgh + roB, &sb[TBH + lo_]);
      }
    }
  };

  auto compute = [&](int buf) {
    const u16* sb = smem + buf * HSM;
    f16x8 fb[4];
#pragma unroll
    for (int n = 0; n < 4; ++n) {
      const int row = wc * 64 + n * 16 + lr;
      const int off = TBH + row * 32 + (((lane >> 4) ^ ((row >> 1) & 3)) << 3);
      fb[n] = __builtin_bit_cast(f16x8, *(const u16x8*)&sb[off]);
    }
    if (AF32) {
      const char* smemb = (const char*)sb;
#pragma unroll
      for (int h = 0; h < 2; ++h) {           // two fa[4] halves: cap live range
        f16x8 fa[4];
#pragma unroll
        for (int m = 0; m < 4; ++m) {
          const int row = wr * 128 + (h * 4 + m) * 16 + lr;
          const int xr = (row & 7) << 4;
          const char* rp = smemb + row * 128;
          const f32x4 p0 = *(const f32x4*)(rp + ((lk << 2) ^ xr));
          const f32x4 p1 = *(const f32x4*)(rp + (((lk << 2) + 16) ^ xr));
          f16x8 va;
          va[0] = (_Float16)p0.x; va[1] = (_Float16)p0.y;
          va[2] = (_Float16)p0.z; va[3] = (_Float16)p0.w;
          va[4] = (_Float16)p1.x; va[5] = (_Float16)p1.y;
          va[6] = (_Float16)p1.z; va[7] = (_Float16)p1.w;
          fa[m] = va;
        }
        __builtin_amdgcn_s_setprio(1);
#pragma unroll
        for (int m = 0; m < 4; ++m)
#pragma unroll
          for (int n = 0; n < 4; ++n)
            acc[h * 4 + m][n] =
                __builtin_amdgcn_mfma_f32_16x16x32_f16(fa[m], fb[n], acc[h * 4 + m][n], 0, 0, 0);
        __builtin_amdgcn_s_setprio(0);
      }
    } else {
      f16x8 fa[4];
#pragma unroll
      for (int m = 0; m < 4; ++m) {
        const int row = wr * 64 + m * 16 + lr;
        const int off = row * 32 + (((lane >> 4) ^ ((row >> 1) & 3)) << 3);
        fa[m] = __builtin_bit_cast(f16x8, *(const u16x8*)&sb[off]);
      }
      __builtin_amdgcn_s_setprio(1);
#pragma unroll
      for (int m = 0; m < 4; ++m)
#pragma unroll
        for (int n = 0; n < 4; ++n)
          acc[m][n] = __builtin_amdgcn_mfma_f32_16x16x32_f16(fa[m], fb[n], acc[m][n], 0, 0, 0);
      __builtin_amdgcn_s_setprio(0);
    }
  };

  // T4 counted-vmcnt pipeline, 2 buffers, 2 raw barriers/iter.
  const int nSteps = K >> 5;
  stage(0, 0);
  for (int t = 0; t < nSteps; ++t) {
    const int cur = t & 1;
    if (t + 1 < nSteps) {
      stage(cur ^ 1, (t + 1) << 5);          // LPS new loads in flight
      vmwait<LPS>();                         // batch t landed
    } else {
      vmwait<0>();                           // final drain
    }
    __builtin_amdgcn_s_barrier();            // all waves' batch-t in LDS
    __builtin_amdgcn_sched_barrier(0);       // no ds_read hoist above (rule 18)
    compute(cur);
    __builtin_amdgcn_sched_barrier(0);       // no ds_read sink below
    __builtin_amdgcn_s_barrier();            // readers done before overwrite
  }

  const int rloc = (lane >> 4) << 2;
  float* o3 = (float*)(half ? out2 : out1);
#pragma unroll
  for (int m = 0; m < MFRAG; ++m) {
#pragma unroll
    for (int n = 0; n < 4; ++n) {
      const int col = colBase + wc * 64 + n * 16 + lr;
#pragma unroll
      for (int j = 0; j < 4; ++j) {
        const long row = rowBase + wr * (MROWS / 2) + m * 16 + rloc + j;
        const float v = acc[m][n][j];
        if (EPI == 1) {
          ((float*)out1)[row * (long)ldOut + col] =
              (v + bias[col] + extra[row * (long)ldOut + col]) * scale;
        } else if (EPI == 3) {
          o3[row * (long)ldOut + col] = v;
        } else if (EPI == 6) {
          ((u16*)out1)[row * (long)ldOut + col] = f2h(v * scale);
        }
      }
    }
  }
}

extern "C" void kernel_launch(void* const* d_in, const int* in_sizes, int n_in,
                              void* d_out, int out_size, void* d_ws, size_t ws_size,
                              hipStream_t stream) {
  (void)in_sizes; (void)n_in; (void)out_size; (void)ws_size;
  const float* x     = (const float*)d_in[0];
  const float* we    = (const float*)d_in[1];
  const float* conv  = (const float*)d_in[2];
  const float* in_v  = (const float*)d_in[3];
  const float* in_g  = (const float*)d_in[4];
  const float* in_b  = (const float*)d_in[5];
  const float* out_v = (const float*)d_in[6];
  const float* out_g = (const float*)d_in[7];
  const float* out_b = (const float*)d_in[8];
  float* out  = (float*)d_out;
  float* attn = out + 33554432l;  // B*L*C floats, then B*L*196

  char* ws = (char*)d_ws;
  u16* concat = (u16*)(ws);                  // f16 [32][256][2048]: cols 0..1023 Zi | 1024.. y
  u16* wtf    = (u16*)(ws + 33554432l);      // Wt f16 [1024][1024] (transposed Wi)
  u16* wo     = (u16*)(ws + 35651584l);      // Wo f16 [1024][1024]
  u16* zo     = (u16*)(ws + 37748736l);      // Zo f16 [32][1024][256] (x14 folded)
  u16* attf   = (u16*)(ws + 54525952l);      // attn f16 [32768][256]
  float* rc   = (float*)(ws + 71303168l);    // [32][256]
  float* s1   = (float*)(ws + 71368704l);    // K-split half-1 scores [32768][256]
  float* s0   = out;                         // K-split half-0 scores in out region

  hipMemsetAsync(rc, 0, 32 * 256 * sizeof(float), stream);
  wnorm_t_kernel<<<1024, 256, 0, stream>>>(in_v, in_g, wtf);
  wnorm_kernel<<<1024, 256, 0, stream>>>(out_v, out_g, wo);
  prep_y_kernel<<<512, 256, 0, stream>>>(conv, in_b, concat, rc);
  // Zi^T[b*256+v][c] = sum_e y[b][v][e] * Wt[c][e], single-f16 MFMA,
  // A = y half of concat, out f16 into concat cols 0..1023 (M=8192,N=1024,K=1024)
  gemm128<6, 3><<<512, 256, 0, stream>>>(
      concat + 1024, nullptr, nullptr, 0, wtf,
      1024, 1024, 2048, 1024, 2048, 0, 0, 0, 0, nullptr, nullptr, 1.f, concat, nullptr);
  // scores = [x|we] @ [Zi;y], f16 MFMA, 256x128 tile, K-split halves (grid 2x256):
  // half0: x@Zi -> s0 ; half1: we@y -> s1  (per-half K=1024; A f32->f16 in-reg)
  gemm128<3, 2><<<512, 256, 0, stream>>>(
      nullptr, x, we, 1024, concat,
      256, 1024, 1024, 2048, 256, 4, 524288l, 0, 1, nullptr, nullptr, 1.f, s0, s1);
  softmax_kernel<<<8192, 256, 0, stream>>>(s0, s1, rc, attn, attf);
  // Zo[b*1024+c][v] = 14 * sum_e Wo[c][e] * y[b][v][e] -> f16
  // (M=32768,N=256,K=1024; A=Wo replicated per batch, B=y half of concat batched)
  gemm128<6, 3><<<512, 256, 0, stream>>>(
      wo, nullptr, nullptr, 0, concat + 1024,
      256, 1024, 1024, 2048, 256, 8, 524288l, 8, 0, nullptr, nullptr, 14.f, zo, nullptr);
  // out = (attf @ Zo^T + out_b + x) * sqrt(0.5)  (M=32768, N=1024, K=256)
  gemm128<1, 3><<<2048, 256, 0, stream>>>(
      attf, nullptr, nullptr, 0, zo,
      1024, 256, 256, 256, 1024, 8, 262144l, 0, 0, out_b, x, SQHF, out, nullptr);
}

// Round 13
// 290.761 us; speedup vs baseline: 1.0577x; 1.0461x over previous
//
#include <hip/hip_runtime.h>
#include <hip/hip_bf16.h>

typedef unsigned short u16;
typedef _Float16 f16x8 __attribute__((ext_vector_type(8)));
typedef unsigned short u16x8 __attribute__((ext_vector_type(8)));
typedef float f32x4 __attribute__((ext_vector_type(4)));

#define SQHF 0.70710678118654752440f

__device__ __forceinline__ u16 f2h(float f) {
  const _Float16 h = (_Float16)f;  // RNE
  return __builtin_bit_cast(u16, h);
}

template <int N>
__device__ __forceinline__ void vmwait() {
  asm volatile("s_waitcnt vmcnt(%0)" ::"i"(N) : "memory");
}

// async global->LDS, 16B per lane; LDS dest is wave-uniform base + lane*16
__device__ __forceinline__ void gload_lds16(const void* g, void* l) {
  __builtin_amdgcn_global_load_lds(
      (const __attribute__((address_space(1))) unsigned int*)g,
      (__attribute__((address_space(3))) unsigned int*)l, 16, 0, 0);
}

__device__ __forceinline__ float block_sum(float v) {
#pragma unroll
  for (int o = 32; o; o >>= 1) v += __shfl_xor(v, o);
  __shared__ float red[4];
  if ((threadIdx.x & 63) == 0) red[threadIdx.x >> 6] = v;
  __syncthreads();
  return red[0] + red[1] + red[2] + red[3];
}

// weight-norm of in_v rows (dim E over C), store TRANSPOSED f16 Wt[c][e]
__global__ void wnorm_t_kernel(const float* __restrict__ v, const float* __restrict__ g,
                               u16* __restrict__ wtf) {
  const int e = blockIdx.x;
  const float* vr = v + (long)e * 1024;
  float ss = 0.f;
  for (int c = threadIdx.x; c < 1024; c += 256) { float t = vr[c]; ss += t * t; }
  const float tot = block_sum(ss);
  const float scl = g[e] / sqrtf(tot);
  for (int c = threadIdx.x; c < 1024; c += 256) wtf[(long)c * 1024 + e] = f2h(vr[c] * scl);
}

// weight-norm of out_v rows (dim C over E), natural layout f16 (A for Zo GEMM)
__global__ void wnorm_kernel(const float* __restrict__ v, const float* __restrict__ g,
                             u16* __restrict__ w) {
  const int c = blockIdx.x;
  const float* vr = v + (long)c * 1024;
  float ss = 0.f;
  for (int e = threadIdx.x; e < 1024; e += 256) { float t = vr[e]; ss += t * t; }
  const float tot = block_sum(ss);
  const float scl = g[c] / sqrtf(tot);
  for (int e = threadIdx.x; e < 1024; e += 256) w[(long)c * 1024 + e] = f2h(vr[e] * scl);
}

// conv_feats [B,1024,196] -> y_t f16 into concat cols 1024..2047 (rows v>=196 zero)
// + rc[b][v] += sum_{e in chunk} in_b[e]*y[b,e,v] via f32 atomics (rc pre-zeroed).
__global__ void prep_y_kernel(const float* __restrict__ conv, const float* __restrict__ in_b,
                              u16* __restrict__ concat, float* __restrict__ rc) {
  const int b = blockIdx.x >> 4;
  const int e0 = (blockIdx.x & 15) << 6;
  __shared__ float tile[64 * 224];
  const float* cb = conv + ((long)b * 1024 + e0) * 196;
  for (int idx = threadIdx.x; idx < 64 * 224; idx += 256) {
    const int rr = idx / 224, vv = idx - rr * 224;
    tile[idx] = (vv < 196) ? cb[(long)rr * 196 + vv] : 0.f;
  }
  __syncthreads();
  for (int idx = threadIdx.x; idx < 256 * 64; idx += 256) {
    const int vr = idx >> 6, c = idx & 63;
    const float val = (vr < 224) ? tile[c * 224 + vr] : 0.f;
    concat[((long)b * 256 + vr) * 2048 + 1024 + e0 + c] = f2h(val);
  }
  const int v = threadIdx.x;
  if (v < 196) {
    float s = 0.f;
#pragma unroll 8
    for (int rr = 0; rr < 64; ++rr) s += in_b[e0 + rr] * tile[rr * 224 + v];
    atomicAdd(&rc[b * 256 + v], s);
  }
}

// scores = s0+s1 (K-split halves) +rc, *sqrt(1/2) -> attn f32 [M][196] + attn f16 [M][256]
__global__ void softmax_kernel(const float* __restrict__ s0b, const float* __restrict__ s1b,
                               const float* __restrict__ rc,
                               float* __restrict__ attn, u16* __restrict__ attn_f) {
  const long row = (long)blockIdx.x * 4 + (threadIdx.x >> 6);
  const int lane = threadIdx.x & 63;
  const int b = (int)(row >> 10);
  const float* s0 = s0b + row * 256;
  const float* s1 = s1b + row * 256;
  const float* rcb = rc + b * 256;
  float v0 = (s0[lane] + s1[lane] + rcb[lane]) * SQHF;
  float v1 = (s0[64 + lane] + s1[64 + lane] + rcb[64 + lane]) * SQHF;
  float v2 = (s0[128 + lane] + s1[128 + lane] + rcb[128 + lane]) * SQHF;
  float v3 = (lane < 4) ? (s0[192 + lane] + s1[192 + lane] + rcb[192 + lane]) * SQHF : -1e30f;
  float mx = fmaxf(fmaxf(v0, v1), fmaxf(v2, v3));
#pragma unroll
  for (int o = 32; o; o >>= 1) mx = fmaxf(mx, __shfl_xor(mx, o));
  const float e0 = __expf(v0 - mx), e1 = __expf(v1 - mx), e2 = __expf(v2 - mx);
  const float e3 = (lane < 4) ? __expf(v3 - mx) : 0.f;
  float sm = e0 + e1 + e2 + e3;
#pragma unroll
  for (int o = 32; o; o >>= 1) sm += __shfl_xor(sm, o);
  const float inv = 1.f / sm;
  float* arow = attn + row * 196;
  arow[lane] = e0 * inv;
  arow[64 + lane] = e1 * inv;
  arow[128 + lane] = e2 * inv;
  if (lane < 4) arow[192 + lane] = e3 * inv;
  u16* brow = attn_f + row * 256;
  brow[lane] = f2h(e0 * inv);
  brow[64 + lane] = f2h(e1 * inv);
  brow[128 + lane] = f2h(e2 * inv);
  brow[192 + lane] = (lane < 4) ? f2h(e3 * inv) : (u16)0;
}

// SCORES kernel: 256x256 tile, 512 threads (8 waves 2Mx4N), grid = 2 halves x
// 128 mTiles = 256 blocks (1/CU). R12 post-mortem: scores is DELIVERY-bound
// (staged bytes / ~6 TB/s across all schedules); numN=2 staged A twice. Full-N
// tile stages A exactly once: 655 -> ~400 MB. A = f32 global (x|we by K-half)
// reg-staged -> f16 LDS (R11-proven, conflicts=0); B = concat f16 via
// global_load_lds. Counted-vmcnt two-phase pipeline (A=4 + B=2 vm-ops/stage):
// steady vmcnt(6) retires B(t); post-barrier vmcnt(2) retires A(t+1) regs.
__global__ __launch_bounds__(512) void gemm_scores(
    const float* __restrict__ Af0, const float* __restrict__ Af1,
    const u16* __restrict__ Bh, long bStride,
    float* __restrict__ out0, float* __restrict__ out1) {
  constexpr int TBH = 8192;    // B tile base (u16 slots)
  constexpr int HSM = 16384;   // per-buffer u16 slots (32KB)
  __shared__ __align__(16) u16 smem[HSM * 2];

  int bid = blockIdx.x;
  const int half = bid & 1;
  bid >>= 1;
  const int nwg = gridDim.x >> 1;            // 128
  const int q = nwg >> 3, xcd = bid & 7, l8 = bid >> 3;
  const int mTile = xcd * q + l8;            // bijective (nwg%8==0)
  const long rowBase = (long)mTile << 8;     // *256
  const int kOff = half << 10;

  const long bOff = (long)(mTile >> 2) * bStride;  // 4 mTiles per batch
  const u16* Bg = Bh + bOff;

  const int tid = threadIdx.x;
  const int wave = tid >> 6, lane = tid & 63;
  const int wr = wave >> 2, wc = wave & 3;   // 2M x 4N
  const int lr = lane & 15;

  // B staging geometry (512 threads, 256 rows x 32 f16 per step, 2 gloads)
  const int sbr = tid >> 2;                  // 0..127 (row within 128-half)
  const int sbc = tid & 3;
  // A reg-staging geometry: arow=tid>>1 (0..255), chunks akch and akch+2 (8 f32 each)
  const int arow = tid >> 1, akch = tid & 1;
  const int aswz = (arow >> 1) & 3;
  const int aoff0 = arow * 32 + ((akch ^ aswz) << 3);
  const int aoff1 = arow * 32 + (((akch + 2) ^ aswz) << 3);

  f32x4 acc[8][4];
#pragma unroll
  for (int m = 0; m < 8; ++m)
#pragma unroll
    for (int n = 0; n < 4; ++n) acc[m][n] = f32x4{0.f, 0.f, 0.f, 0.f};

  f32x4 ra0, ra1, rb0, rb1;  // A in-flight regs (single named set, rule #20)
  auto issueA = [&](int k0) {
    const int gk = k0 + kOff;
    const float* As = (gk < 1024) ? (Af0 + rowBase * 1024 + gk)
                                  : (Af1 + rowBase * 1024 + (gk - 1024));
    const float* p = As + (long)arow * 1024 + akch * 8;
    ra0 = *(const f32x4*)p;        ra1 = *(const f32x4*)(p + 4);
    rb0 = *(const f32x4*)(p + 16); rb1 = *(const f32x4*)(p + 20);
  };
  auto writeA = [&](int buf) {
    u16* sb = smem + buf * HSM;
    u16x8 w0, w1;
    w0[0] = f2h(ra0[0]); w0[1] = f2h(ra0[1]); w0[2] = f2h(ra0[2]); w0[3] = f2h(ra0[3]);
    w0[4] = f2h(ra1[0]); w0[5] = f2h(ra1[1]); w0[6] = f2h(ra1[2]); w0[7] = f2h(ra1[3]);
    w1[0] = f2h(rb0[0]); w1[1] = f2h(rb0[1]); w1[2] = f2h(rb0[2]); w1[3] = f2h(rb0[3]);
    w1[4] = f2h(rb1[0]); w1[5] = f2h(rb1[1]); w1[6] = f2h(rb1[2]); w1[7] = f2h(rb1[3]);
    *(u16x8*)&sb[aoff0] = w0;
    *(u16x8*)&sb[aoff1] = w1;
  };
  auto stageB = [&](int buf, int k0) {
    u16* sb = smem + buf * HSM;
#pragma unroll
    for (int i = 0; i < 2; ++i) {
      const int row = i * 128 + sbr;
      const int csw = ((sbc ^ ((row >> 1) & 3)) << 3);
      gload_lds16(Bg + (long)row * 2048 + k0 + kOff + csw,
                  &smem[buf * HSM + TBH + i * 4096 + wave * 512]);
      (void)sb;
    }
  };

  auto compute = [&](int buf) {
    const u16* sb = smem + buf * HSM;
    f16x8 fb[4];
#pragma unroll
    for (int n = 0; n < 4; ++n) {
      const int row = wc * 64 + n * 16 + lr;
      const int off = TBH + row * 32 + (((lane >> 4) ^ ((row >> 1) & 3)) << 3);
      fb[n] = __builtin_bit_cast(f16x8, *(const u16x8*)&sb[off]);
    }
#pragma unroll
    for (int h = 0; h < 2; ++h) {
      f16x8 fa[4];
#pragma unroll
      for (int m = 0; m < 4; ++m) {
        const int row = wr * 128 + (h * 4 + m) * 16 + lr;
        const int off = row * 32 + (((lane >> 4) ^ ((row >> 1) & 3)) << 3);
        fa[m] = __builtin_bit_cast(f16x8, *(const u16x8*)&sb[off]);
      }
      __builtin_amdgcn_s_setprio(1);
#pragma unroll
      for (int m = 0; m < 4; ++m)
#pragma unroll
        for (int n = 0; n < 4; ++n)
          acc[h * 4 + m][n] =
              __builtin_amdgcn_mfma_f32_16x16x32_f16(fa[m], fb[n], acc[h * 4 + m][n], 0, 0, 0);
      __builtin_amdgcn_s_setprio(0);
    }
  };

  const int nSteps = 32;  // K=1024 per half
  issueA(0); stageB(0, 0);                   // 6 outstanding
  vmwait<2>();                               // A(0) regs landed
  writeA(0);
  issueA(32); stageB(1, 32);                 // <=8 outstanding
  for (int t = 0; t < nSteps; ++t) {
    if (t + 1 < nSteps) {
      asm volatile("s_waitcnt vmcnt(6) lgkmcnt(0)" ::: "memory");  // B(t)+A-writes done
    } else {
      asm volatile("s_waitcnt vmcnt(0) lgkmcnt(0)" ::: "memory");
    }
    __builtin_amdgcn_s_barrier();
    __builtin_amdgcn_sched_barrier(0);       // rule #18 fence
    compute(t & 1);
    __builtin_amdgcn_sched_barrier(0);
    __builtin_amdgcn_s_barrier();
    if (t + 1 < nSteps) {
      vmwait<2>();                           // A(t+1) regs landed
      writeA((t + 1) & 1);
      if (t + 2 < nSteps) { issueA((t + 2) << 5); stageB(t & 1, (t + 2) << 5); }
    }
  }

  float* o = half ? out1 : out0;
  const int rloc = (lane >> 4) << 2;
#pragma unroll
  for (int m = 0; m < 8; ++m) {
#pragma unroll
    for (int n = 0; n < 4; ++n) {
      const int col = wc * 64 + n * 16 + lr;
#pragma unroll
      for (int j = 0; j < 4; ++j) {
        const long row = rowBase + wr * 128 + m * 16 + rloc + j;
        o[row * 256 + col] = acc[m][n][j];
      }
    }
  }
}

// 128x128-tile fp16 MFMA GEMM (MODE 3), B^T-layout operands, T4 counted-vmcnt
// pipeline (R8-validated). A,B f16 via global_load_lds; 4 loads/stage; 32KB LDS.
// f16 LDS tiles use chunk-XOR swizzle (row>>1)&3 on both stage-src and read.
// EPI: 1=(acc+bias[col]+extra[row*ldOut+col])*scale -> f32
//      6=(_Float16)(acc*scale) -> f16
// NOTE: NO min-waves clause (R3: (256,4)->spills; R4: (256,2)->lost ILP).
template <int EPI>
__global__ __launch_bounds__(256) void gemm128(
    const u16* __restrict__ Ah, const u16* __restrict__ Bh,
    int N, int K, int ldA, int ldB, int ldOut,
    int mTilesPerBatch, long bStride, int aTilesMod,
    const float* __restrict__ bias, const float* __restrict__ extra,
    float scale, void* __restrict__ out1) {
  constexpr int TBH = 4096;
  constexpr int HSM = 8192;
  __shared__ __align__(16) u16 smem[HSM * 2];

  const int bid = blockIdx.x, nwg = gridDim.x;
  const int numN = N >> 7;
  const int q = nwg >> 3, r = nwg & 7, xcd = bid & 7, l8 = bid >> 3;
  const int wg = (xcd < r ? xcd * (q + 1) : r * (q + 1) + (xcd - r) * q) + l8;
  const int mTile = wg / numN, nTile = wg - mTile * numN;
  const long rowBase = (long)mTile << 7;
  const int colBase = nTile << 7;
  const int aTile = aTilesMod ? (mTile % aTilesMod) : mTile;
  const long aRowBase = (long)aTile << 7;
  const long bOff = mTilesPerBatch ? (long)(mTile / mTilesPerBatch) * bStride : 0;

  const u16* Agh = Ah + aRowBase * ldA;
  const u16* Bgh = Bh + bOff + (long)colBase * ldB;

  const int tid = threadIdx.x;
  const int wave = tid >> 6, lane = tid & 63;
  const int wr = wave >> 1, wc = wave & 1;
  const int sr = wave * 16 + (lane >> 2);
  const int scS = (((lane & 3) ^ ((sr >> 1) & 3)) << 3);
  const int lr = lane & 15;

  f32x4 acc[4][4];
#pragma unroll
  for (int m = 0; m < 4; ++m)
#pragma unroll
    for (int n = 0; n < 4; ++n) acc[m][n] = f32x4{0.f, 0.f, 0.f, 0.f};

  auto stage = [&](int buf, int k0) {
    u16* sb = smem + buf * HSM;
#pragma unroll
    for (int i = 0; i < 2; ++i) {
      const long roA = (long)(i * 64 + sr) * ldA + k0 + scS;
      const long roB = (long)(i * 64 + sr) * ldB + k0 + scS;
      const int lo_ = i * 2048 + wave * 512;
      gload_lds16(Agh + roA, &sb[lo_]);
      gload_lds16(Bgh + roB, &sb[TBH + lo_]);
    }
  };

  auto compute = [&](int buf) {
    const u16* sb = smem + buf * HSM;
    f16x8 fa[4], fb[4];
#pragma unroll
    for (int m = 0; m < 4; ++m) {
      const int row = wr * 64 + m * 16 + lr;
      const int off = row * 32 + (((lane >> 4) ^ ((row >> 1) & 3)) << 3);
      fa[m] = __builtin_bit_cast(f16x8, *(const u16x8*)&sb[off]);
    }
#pragma unroll
    for (int n = 0; n < 4; ++n) {
      const int row = wc * 64 + n * 16 + lr;
      const int off = row * 32 + (((lane >> 4) ^ ((row >> 1) & 3)) << 3);
      fb[n] = __builtin_bit_cast(f16x8, *(const u16x8*)&sb[TBH + off]);
    }
    __builtin_amdgcn_s_setprio(1);
#pragma unroll
    for (int m = 0; m < 4; ++m)
#pragma unroll
      for (int n = 0; n < 4; ++n)
        acc[m][n] = __builtin_amdgcn_mfma_f32_16x16x32_f16(fa[m], fb[n], acc[m][n], 0, 0, 0);
    __builtin_amdgcn_s_setprio(0);
  };

  const int nSteps = K >> 5;
  stage(0, 0);
  for (int t = 0; t < nSteps; ++t) {
    const int cur = t & 1;
    if (t + 1 < nSteps) {
      stage(cur ^ 1, (t + 1) << 5);
      vmwait<4>();
    } else {
      vmwait<0>();
    }
    __builtin_amdgcn_s_barrier();
    __builtin_amdgcn_sched_barrier(0);
    compute(cur);
    __builtin_amdgcn_sched_barrier(0);
    __builtin_amdgcn_s_barrier();
  }

  const int rloc = (lane >> 4) << 2;
#pragma unroll
  for (int m = 0; m < 4; ++m) {
#pragma unroll
    for (int n = 0; n < 4; ++n) {
      const int col = colBase + wc * 64 + n * 16 + lr;
#pragma unroll
      for (int j = 0; j < 4; ++j) {
        const long row = rowBase + wr * 64 + m * 16 + rloc + j;
        const float v = acc[m][n][j];
        if (EPI == 1) {
          ((float*)out1)[row * (long)ldOut + col] =
              (v + bias[col] + extra[row * (long)ldOut + col]) * scale;
        } else if (EPI == 6) {
          ((u16*)out1)[row * (long)ldOut + col] = f2h(v * scale);
        }
      }
    }
  }
}

extern "C" void kernel_launch(void* const* d_in, const int* in_sizes, int n_in,
                              void* d_out, int out_size, void* d_ws, size_t ws_size,
                              hipStream_t stream) {
  (void)in_sizes; (void)n_in; (void)out_size; (void)ws_size;
  const float* x     = (const float*)d_in[0];
  const float* we    = (const float*)d_in[1];
  const float* conv  = (const float*)d_in[2];
  const float* in_v  = (const float*)d_in[3];
  const float* in_g  = (const float*)d_in[4];
  const float* in_b  = (const float*)d_in[5];
  const float* out_v = (const float*)d_in[6];
  const float* out_g = (const float*)d_in[7];
  const float* out_b = (const float*)d_in[8];
  float* out  = (float*)d_out;
  float* attn = out + 33554432l;  // B*L*C floats, then B*L*196

  char* ws = (char*)d_ws;
  u16* concat = (u16*)(ws);                  // f16 [32][256][2048]: cols 0..1023 Zi | 1024.. y
  u16* wtf    = (u16*)(ws + 33554432l);      // Wt f16 [1024][1024] (transposed Wi)
  u16* wo     = (u16*)(ws + 35651584l);      // Wo f16 [1024][1024]
  u16* zo     = (u16*)(ws + 37748736l);      // Zo f16 [32][1024][256] (x14 folded)
  u16* attf   = (u16*)(ws + 54525952l);      // attn f16 [32768][256]
  float* rc   = (float*)(ws + 71303168l);    // [32][256]
  float* s1   = (float*)(ws + 71368704l);    // K-split half-1 scores [32768][256]
  float* s0   = out;                         // K-split half-0 scores in out region

  hipMemsetAsync(rc, 0, 32 * 256 * sizeof(float), stream);
  wnorm_t_kernel<<<1024, 256, 0, stream>>>(in_v, in_g, wtf);
  wnorm_kernel<<<1024, 256, 0, stream>>>(out_v, out_g, wo);
  prep_y_kernel<<<512, 256, 0, stream>>>(conv, in_b, concat, rc);
  // Zi^T[b*256+v][c] = sum_e y[b][v][e] * Wt[c][e], single-f16 MFMA,
  // A = y half of concat, out f16 into concat cols 0..1023 (M=8192,N=1024,K=1024)
  gemm128<6><<<512, 256, 0, stream>>>(
      concat + 1024, wtf, 1024, 1024, 2048, 1024, 2048,
      0, 0, 0, nullptr, nullptr, 1.f, concat);
  // scores = [x|we] @ [Zi;y], 256x256 tile, A staged once (grid 2x128):
  // half0: x@Zi -> s0 ; half1: we@y -> s1
  gemm_scores<<<256, 512, 0, stream>>>(x, we, concat, 524288l, s0, s1);
  softmax_kernel<<<8192, 256, 0, stream>>>(s0, s1, rc, attn, attf);
  // Zo[b*1024+c][v] = 14 * sum_e Wo[c][e] * y[b][v][e] -> f16
  // (M=32768,N=256,K=1024; A=Wo replicated per batch, B=y half of concat batched)
  gemm128<6><<<512, 256, 0, stream>>>(
      wo, concat + 1024, 256, 1024, 1024, 2048, 256,
      8, 524288l, 8, nullptr, nullptr, 14.f, zo);
  // out = (attf @ Zo^T + out_b + x) * sqrt(0.5)  (M=32768, N=1024, K=256)
  gemm128<1><<<2048, 256, 0, stream>>>(
      attf, zo, 1024, 256, 256, 256, 1024,
      8, 262144l, 0, out_b, x, SQHF, out);
}